// Round 18
// baseline (280.922 us; speedup 1.0000x reference)
//
#include <hip/hip_runtime.h>
#include <hip/hip_bf16.h>

typedef short bh8 __attribute__((ext_vector_type(8)));
typedef char  i8x8 __attribute__((ext_vector_type(8)));
typedef char  i8x16 __attribute__((ext_vector_type(16)));
typedef float f32x4 __attribute__((ext_vector_type(4)));

#define NBLOCKS_MAIN 512
#define PNODES 16

__device__ __forceinline__ short f2bf(float f) {
  __hip_bfloat16 h = __float2bfloat16(f);
  return *reinterpret_cast<short*>(&h);
}
__device__ __forceinline__ float bf2f(short s) {
  return __uint_as_float(((uint)(ushort)s) << 16);
}
// fragment permutation v2: pos = q*32 + kf*8 + h*4 + j  (f = kf*32+h*16+q*4+j)
__device__ __forceinline__ int fpos(int f) {
  int kf = (f >> 5) & 3, h = (f >> 4) & 1, q = (f >> 2) & 3, j = f & 3;
  return (q << 5) | (kf << 3) | (h << 2) | j;
}

// ---- kernel 1: Pa = z@W1a + b1, Pb = z@W1b -> int8 rows + f32 scales ----
__global__ __launch_bounds__(256) void precompute_p(
    const float* __restrict__ z, const float* __restrict__ W1,
    const float* __restrict__ b1, char* __restrict__ Pai,
    char* __restrict__ Pbi, float* __restrict__ Pas, float* __restrict__ Pbs,
    int NN) {
  __shared__ float zs[PNODES][128];
  __shared__ float wmax[4][PNODES];
  const int tid = threadIdx.x;
  const int n0 = blockIdx.x * PNODES;
  for (int i = tid; i < PNODES * 128; i += 256) {
    int m = i >> 7, ff = i & 127, n = n0 + m;
    zs[m][ff] = (n < NN) ? z[(size_t)n * 128 + ff] : 0.f;
  }
  __syncthreads();
  const int f = tid & 127;
  const bool isA = tid < 128;
  const float* w = W1 + (isA ? 0 : 128) * 128 + f;
  const float bias = isA ? b1[f] : 0.f;
  float a[PNODES];
#pragma unroll
  for (int m = 0; m < PNODES; ++m) a[m] = bias;
  for (int k = 0; k < 128; ++k) {
    float wv = w[(size_t)k * 128];
#pragma unroll
    for (int m = 0; m < PNODES; ++m) a[m] += zs[m][k] * wv;
  }
  const int wv_ = tid >> 6;
#pragma unroll
  for (int m = 0; m < PNODES; ++m) {
    float v = fabsf(a[m]);
#pragma unroll
    for (int dd = 1; dd < 64; dd <<= 1) v = fmaxf(v, __shfl_xor(v, dd, 64));
    if ((tid & 63) == 0) wmax[wv_][m] = v;
  }
  __syncthreads();
  const int w0 = isA ? 0 : 2;
  char* di = isA ? Pai : Pbi;
  float* ds = isA ? Pas : Pbs;
  const int pos = fpos(f);
#pragma unroll
  for (int m = 0; m < PNODES; ++m) {
    int n = n0 + m;
    if (n < NN) {
      float mx = fmaxf(fmaxf(wmax[w0][m], wmax[w0 + 1][m]), 1e-20f);
      di[(size_t)n * 128 + pos] = (char)(int)rintf(a[m] * (127.0f / mx));
      if (f == 0) ds[n] = mx / 127.0f;
    }
  }
}

// ---- kernel 2: pack W2/W3 into frag-linear bf16 ----
__global__ __launch_bounds__(512) void pack_w(
    const float* __restrict__ W2, const float* __restrict__ W3,
    ushort* __restrict__ w2f, ushort* __restrict__ w3f) {
  int idx = blockIdx.x * 512 + threadIdx.x;
  if (idx >= 16384) return;
  int e = idx & 7, l = (idx >> 3) & 63, kb = (idx >> 9) & 3, ob = idx >> 11;
  int q = l >> 4;
  int k = kb * 32 + (e < 4 ? q * 4 + e : 16 + q * 4 + (e - 4));
  int n = ob * 16 + (l & 15);
  w2f[idx] = (ushort)f2bf(W2[k * 128 + n]);
  w3f[idx] = (ushort)f2bf(W3[k * 128 + n]);
}

// ---- kernel 3: main edge MLP — half-pass structure, no spill ----
struct alignas(16) SMem {
  ushort w2[16384];      // frag-linear: ((ob*4+kf)*64+lane)*8+e
  ushort w3[16384];
  float b2[128], b3[128], w4[128];
  ushort w1gp[128];
};

union U16 { i8x16 v; i8x8 h2[2]; };

__global__ __launch_bounds__(256, 2) void edge_mlp(
    const char* __restrict__ Pai, const char* __restrict__ Pbi,
    const float* __restrict__ Pas, const float* __restrict__ Pbs,
    const ushort* __restrict__ w2f, const ushort* __restrict__ w3f,
    const float* __restrict__ graph, const int* __restrict__ ei,
    const float* __restrict__ W1, const float* __restrict__ b2,
    const float* __restrict__ b3, const float* __restrict__ W4,
    const float* __restrict__ b4, float* __restrict__ out, int E, int NN) {
  __shared__ SMem s;
  const int tid = threadIdx.x;
  {
    const uint4* s2 = (const uint4*)w2f;
    const uint4* s3 = (const uint4*)w3f;
    uint4* d2 = (uint4*)s.w2;
    uint4* d3 = (uint4*)s.w3;
    for (int i = tid; i < 2048; i += 256) { d2[i] = s2[i]; d3[i] = s3[i]; }
    if (tid < 128) {
      s.b2[tid] = b2[tid]; s.b3[tid] = b3[tid]; s.w4[tid] = W4[tid];
      s.w1gp[fpos(tid)] = (ushort)f2bf(W1[256 * 128 + tid]);
    }
  }
  __syncthreads();

  const float b4v = b4[0];
  const int lane = tid & 63;
  const int c = lane & 15;
  const int q = lane >> 4;
  const int wgid = (int)blockIdx.x * 4 + (tid >> 6);
  const int n_tiles = (E + 63) / 64;
  const f32x4 z4 = {0.f, 0.f, 0.f, 0.f};

  bh8 w1gb[4];
#pragma unroll
  for (int kf = 0; kf < 4; ++kf)
    w1gb[kf] = *(const bh8*)&s.w1gp[q * 32 + kf * 8];

  for (int tile = wgid; tile < n_tiles; tile += NBLOCKS_MAIN * 4) {
    const int ebase = tile * 64;

    int se[4], de[4];
    float gv[4], sa[4], sb[4];
#pragma unroll
    for (int et = 0; et < 4; ++et) {
      int e = ebase + et * 16 + c;
      if (e >= E) e = E - 1;
      se[et] = __builtin_nontemporal_load(ei + e);
      de[et] = __builtin_nontemporal_load(ei + E + e);
    }
#pragma unroll
    for (int et = 0; et < 4; ++et)
      gv[et] = __builtin_nontemporal_load(graph + (size_t)se[et] * NN + de[et]);
#pragma unroll
    for (int et = 0; et < 4; ++et) {
      sa[et] = Pas[se[et]];
      sb[et] = Pbs[de[et]];
    }

    // issue ALL row gathers up-front (memory parallelism), hold in regs
    U16 ra[4][2], rb[4][2];
#pragma unroll
    for (int et = 0; et < 4; ++et) {
      const char* par = Pai + (size_t)se[et] * 128 + q * 32;
      const char* pbr = Pbi + (size_t)de[et] * 128 + q * 32;
      ra[et][0].v = *(const i8x16*)par;  ra[et][1].v = *(const i8x16*)(par + 16);
      rb[et][0].v = *(const i8x16*)pbr;  rb[et][1].v = *(const i8x16*)(pbr + 16);
    }

    float psum[4] = {0.f, 0.f, 0.f, 0.f};

#pragma unroll
    for (int half = 0; half < 2; ++half) {
      // ---- layer-1 for 2 edge-subtiles: bp2 = relu(sa*pa + sb*pb + g*w1g) ----
      bh8 bp2[2][4];
#pragma unroll
      for (int e2 = 0; e2 < 2; ++e2) {
        const int et = half * 2 + e2;
        i8x8 pa8[4] = {ra[et][0].h2[0], ra[et][0].h2[1], ra[et][1].h2[0], ra[et][1].h2[1]};
        i8x8 pb8[4] = {rb[et][0].h2[0], rb[et][0].h2[1], rb[et][1].h2[0], rb[et][1].h2[1]};
#pragma unroll
        for (int kf = 0; kf < 4; ++kf) {
          bh8 t8;
#pragma unroll
          for (int i = 0; i < 8; ++i) {
            float v = fmaf((float)pa8[kf][i], sa[et],
                      fmaf((float)pb8[kf][i], sb[et],
                           gv[et] * bf2f(w1gb[kf][i])));
            t8[i] = f2bf(fmaxf(v, 0.f));
          }
          bp2[e2][kf] = t8;
        }
      }

      // ---- layer 2 ----
      f32x4 acc2[2][8];
#pragma unroll
      for (int e2 = 0; e2 < 2; ++e2)
#pragma unroll
        for (int ob = 0; ob < 8; ++ob) acc2[e2][ob] = z4;
#pragma unroll
      for (int kf = 0; kf < 4; ++kf) {
#pragma unroll
        for (int ob = 0; ob < 8; ++ob) {
          bh8 af = *(const bh8*)&s.w2[((ob * 4 + kf) * 64 + lane) * 8];
#pragma unroll
          for (int e2 = 0; e2 < 2; ++e2)
            acc2[e2][ob] = __builtin_amdgcn_mfma_f32_16x16x32_bf16(af, bp2[e2][kf], acc2[e2][ob], 0, 0, 0);
        }
      }
#pragma unroll
      for (int e2 = 0; e2 < 2; ++e2) {
#pragma unroll
        for (int kf = 0; kf < 4; ++kf) {
          bh8 t8;
#pragma unroll
          for (int hh = 0; hh < 2; ++hh) {
            int ob = kf * 2 + hh;
#pragma unroll
            for (int r = 0; r < 4; ++r) {
              int f = ob * 16 + q * 4 + r;
              float v = fmaxf(acc2[e2][ob][r] + s.b2[f], 0.f);
              t8[hh * 4 + r] = f2bf(v);
            }
          }
          bp2[e2][kf] = t8;
        }
      }

      // ---- layer 3 ----
#pragma unroll
      for (int e2 = 0; e2 < 2; ++e2)
#pragma unroll
        for (int ob = 0; ob < 8; ++ob) acc2[e2][ob] = z4;
#pragma unroll
      for (int kf = 0; kf < 4; ++kf) {
#pragma unroll
        for (int ob = 0; ob < 8; ++ob) {
          bh8 af = *(const bh8*)&s.w3[((ob * 4 + kf) * 64 + lane) * 8];
#pragma unroll
          for (int e2 = 0; e2 < 2; ++e2)
            acc2[e2][ob] = __builtin_amdgcn_mfma_f32_16x16x32_bf16(af, bp2[e2][kf], acc2[e2][ob], 0, 0, 0);
        }
      }

      // ---- fused relu3 + layer-4 partial dot ----
#pragma unroll
      for (int e2 = 0; e2 < 2; ++e2) {
        float ps = 0.f;
#pragma unroll
        for (int ob = 0; ob < 8; ++ob) {
#pragma unroll
          for (int r = 0; r < 4; ++r) {
            int f = ob * 16 + q * 4 + r;
            float v = fmaxf(acc2[e2][ob][r] + s.b3[f], 0.f);
            ps += v * s.w4[f];
          }
        }
        psum[half * 2 + e2] = ps;
      }
    }

    // ---- cross-lane reduce + sigmoid + coalesced write ----
#pragma unroll
    for (int et = 0; et < 4; ++et) {
      psum[et] += __shfl_xor(psum[et], 16, 64);
      psum[et] += __shfl_xor(psum[et], 32, 64);
    }
    float vsel = (q == 0) ? psum[0] : (q == 1) ? psum[1] : (q == 2) ? psum[2] : psum[3];
    float val = vsel + b4v;
    float sig = 1.0f / (1.0f + __expf(-val));
    int eout = ebase + lane;
    if (eout < E) __builtin_nontemporal_store(sig, out + eout);
  }
}

extern "C" void kernel_launch(void* const* d_in, const int* in_sizes, int n_in,
                              void* d_out, int out_size, void* d_ws, size_t ws_size,
                              hipStream_t stream) {
  const float* z     = (const float*)d_in[0];
  const float* graph = (const float*)d_in[2];
  const int*   ei    = (const int*)d_in[3];
  const float* W1 = (const float*)d_in[4];
  const float* b1 = (const float*)d_in[5];
  const float* W2 = (const float*)d_in[6];
  const float* b2 = (const float*)d_in[7];
  const float* W3 = (const float*)d_in[8];
  const float* b3 = (const float*)d_in[9];
  const float* W4 = (const float*)d_in[10];
  const float* b4 = (const float*)d_in[11];
  int E  = in_sizes[3] / 2;
  int NN = in_sizes[0] / 128;

  char* w = (char*)d_ws;
  size_t o = 0;
  auto alloc = [&](size_t bytes) { void* p = w + o; o = (o + bytes + 255) & ~(size_t)255; return p; };
  char*   Pai = (char*)alloc((size_t)NN * 128);
  char*   Pbi = (char*)alloc((size_t)NN * 128);
  float*  Pas = (float*)alloc((size_t)NN * 4);
  float*  Pbs = (float*)alloc((size_t)NN * 4);
  ushort* w2f = (ushort*)alloc(16384 * 2);
  ushort* w3f = (ushort*)alloc(16384 * 2);

  hipLaunchKernelGGL(precompute_p, dim3((NN + PNODES - 1) / PNODES), dim3(256), 0, stream,
                     z, W1, b1, Pai, Pbi, Pas, Pbs, NN);
  hipLaunchKernelGGL(pack_w, dim3(32), dim3(512), 0, stream, W2, W3, w2f, w3f);
  hipLaunchKernelGGL(edge_mlp, dim3(NBLOCKS_MAIN), dim3(256), 0, stream,
                     Pai, Pbi, Pas, Pbs, w2f, w3f, graph, ei,
                     W1, b2, b3, W4, b4, (float*)d_out, E, NN);
}

// Round 20
// 116.280 us; speedup vs baseline: 2.4159x; 2.4159x over previous
//
#include <hip/hip_runtime.h>
#include <hip/hip_bf16.h>

typedef short bh8 __attribute__((ext_vector_type(8)));
typedef char  i8x8 __attribute__((ext_vector_type(8)));
typedef char  i8x16 __attribute__((ext_vector_type(16)));
typedef float f32x4 __attribute__((ext_vector_type(4)));

#define NBLOCKS_MAIN 512
#define PNODES 16

__device__ __forceinline__ short f2bf(float f) {
  __hip_bfloat16 h = __float2bfloat16(f);
  return *reinterpret_cast<short*>(&h);
}
__device__ __forceinline__ float bf2f(short s) {
  return __uint_as_float(((uint)(ushort)s) << 16);
}
// fragment permutation v2: pos = q*32 + kf*8 + h*4 + j  (f = kf*32+h*16+q*4+j)
__device__ __forceinline__ int fpos(int f) {
  int kf = (f >> 5) & 3, h = (f >> 4) & 1, q = (f >> 2) & 3, j = f & 3;
  return (q << 5) | (kf << 3) | (h << 2) | j;
}

// ---- kernel 1: Pa = z@W1a + b1, Pb = z@W1b -> int8 rows + f32 scales ----
__global__ __launch_bounds__(256) void precompute_p(
    const float* __restrict__ z, const float* __restrict__ W1,
    const float* __restrict__ b1, char* __restrict__ Pai,
    char* __restrict__ Pbi, float* __restrict__ Pas, float* __restrict__ Pbs,
    int NN) {
  __shared__ float zs[PNODES][128];
  __shared__ float wmax[4][PNODES];
  const int tid = threadIdx.x;
  const int n0 = blockIdx.x * PNODES;
  for (int i = tid; i < PNODES * 128; i += 256) {
    int m = i >> 7, ff = i & 127, n = n0 + m;
    zs[m][ff] = (n < NN) ? z[(size_t)n * 128 + ff] : 0.f;
  }
  __syncthreads();
  const int f = tid & 127;
  const bool isA = tid < 128;
  const float* w = W1 + (isA ? 0 : 128) * 128 + f;
  const float bias = isA ? b1[f] : 0.f;
  float a[PNODES];
#pragma unroll
  for (int m = 0; m < PNODES; ++m) a[m] = bias;
  for (int k = 0; k < 128; ++k) {
    float wv = w[(size_t)k * 128];
#pragma unroll
    for (int m = 0; m < PNODES; ++m) a[m] += zs[m][k] * wv;
  }
  const int wv_ = tid >> 6;
#pragma unroll
  for (int m = 0; m < PNODES; ++m) {
    float v = fabsf(a[m]);
#pragma unroll
    for (int dd = 1; dd < 64; dd <<= 1) v = fmaxf(v, __shfl_xor(v, dd, 64));
    if ((tid & 63) == 0) wmax[wv_][m] = v;
  }
  __syncthreads();
  const int w0 = isA ? 0 : 2;
  char* di = isA ? Pai : Pbi;
  float* ds = isA ? Pas : Pbs;
  const int pos = fpos(f);
#pragma unroll
  for (int m = 0; m < PNODES; ++m) {
    int n = n0 + m;
    if (n < NN) {
      float mx = fmaxf(fmaxf(wmax[w0][m], wmax[w0 + 1][m]), 1e-20f);
      di[(size_t)n * 128 + pos] = (char)(int)rintf(a[m] * (127.0f / mx));
      if (f == 0) ds[n] = mx / 127.0f;
    }
  }
}

// ---- kernel 2: pack W2/W3 into frag-linear bf16 ----
__global__ __launch_bounds__(512) void pack_w(
    const float* __restrict__ W2, const float* __restrict__ W3,
    ushort* __restrict__ w2f, ushort* __restrict__ w3f) {
  int idx = blockIdx.x * 512 + threadIdx.x;
  if (idx >= 16384) return;
  int e = idx & 7, l = (idx >> 3) & 63, kb = (idx >> 9) & 3, ob = idx >> 11;
  int q = l >> 4;
  int k = kb * 32 + (e < 4 ? q * 4 + e : 16 + q * 4 + (e - 4));
  int n = ob * 16 + (l & 15);
  w2f[idx] = (ushort)f2bf(W2[k * 128 + n]);
  w3f[idx] = (ushort)f2bf(W3[k * 128 + n]);
}

// ---- kernel 3: main edge MLP — R17 structure, layer-1 in 2 halves (anti-spill) ----
struct alignas(16) SMem {
  ushort w2[16384];      // frag-linear: ((ob*4+kf)*64+lane)*8+e
  ushort w3[16384];
  float b2[128], b3[128], w4[128];
  ushort w1gp[128];
};

union U16 { i8x16 v; i8x8 h2[2]; };

__global__ __launch_bounds__(256, 2) void edge_mlp(
    const char* __restrict__ Pai, const char* __restrict__ Pbi,
    const float* __restrict__ Pas, const float* __restrict__ Pbs,
    const ushort* __restrict__ w2f, const ushort* __restrict__ w3f,
    const float* __restrict__ graph, const int* __restrict__ ei,
    const float* __restrict__ W1, const float* __restrict__ b2,
    const float* __restrict__ b3, const float* __restrict__ W4,
    const float* __restrict__ b4, float* __restrict__ out, int E, int NN) {
  __shared__ SMem s;
  const int tid = threadIdx.x;
  {
    const uint4* s2 = (const uint4*)w2f;
    const uint4* s3 = (const uint4*)w3f;
    uint4* d2 = (uint4*)s.w2;
    uint4* d3 = (uint4*)s.w3;
    for (int i = tid; i < 2048; i += 256) { d2[i] = s2[i]; d3[i] = s3[i]; }
    if (tid < 128) {
      s.b2[tid] = b2[tid]; s.b3[tid] = b3[tid]; s.w4[tid] = W4[tid];
      s.w1gp[fpos(tid)] = (ushort)f2bf(W1[256 * 128 + tid]);
    }
  }
  __syncthreads();

  const float b4v = b4[0];
  const int lane = tid & 63;
  const int c = lane & 15;
  const int q = lane >> 4;
  const int wgid = (int)blockIdx.x * 4 + (tid >> 6);
  const int n_tiles = (E + 63) / 64;
  const f32x4 z4 = {0.f, 0.f, 0.f, 0.f};

  bh8 w1gb[4];
#pragma unroll
  for (int kf = 0; kf < 4; ++kf)
    w1gb[kf] = *(const bh8*)&s.w1gp[q * 32 + kf * 8];

  for (int tile = wgid; tile < n_tiles; tile += NBLOCKS_MAIN * 4) {
    const int ebase = tile * 64;

    int se[4], de[4];
    float gv[4], sa[4], sb[4];
#pragma unroll
    for (int et = 0; et < 4; ++et) {
      int e = ebase + et * 16 + c;
      if (e >= E) e = E - 1;
      se[et] = __builtin_nontemporal_load(ei + e);
      de[et] = __builtin_nontemporal_load(ei + E + e);
    }
#pragma unroll
    for (int et = 0; et < 4; ++et)
      gv[et] = __builtin_nontemporal_load(graph + (size_t)se[et] * NN + de[et]);
#pragma unroll
    for (int et = 0; et < 4; ++et) {
      sa[et] = Pas[se[et]];
      sb[et] = Pbs[de[et]];
    }

    // ---- layer-1 in two halves: only 2 subtiles' rows live at a time ----
    bh8 bp[4][4];
#pragma unroll
    for (int hp = 0; hp < 2; ++hp) {
      U16 ra2[2][2], rb2[2][2];
#pragma unroll
      for (int e2 = 0; e2 < 2; ++e2) {
        const int et = hp * 2 + e2;
        const char* par = Pai + (size_t)se[et] * 128 + q * 32;
        const char* pbr = Pbi + (size_t)de[et] * 128 + q * 32;
        ra2[e2][0].v = *(const i8x16*)par;  ra2[e2][1].v = *(const i8x16*)(par + 16);
        rb2[e2][0].v = *(const i8x16*)pbr;  rb2[e2][1].v = *(const i8x16*)(pbr + 16);
      }
#pragma unroll
      for (int e2 = 0; e2 < 2; ++e2) {
        const int et = hp * 2 + e2;
        i8x8 pa8[4] = {ra2[e2][0].h2[0], ra2[e2][0].h2[1], ra2[e2][1].h2[0], ra2[e2][1].h2[1]};
        i8x8 pb8[4] = {rb2[e2][0].h2[0], rb2[e2][0].h2[1], rb2[e2][1].h2[0], rb2[e2][1].h2[1]};
#pragma unroll
        for (int kf = 0; kf < 4; ++kf) {
          bh8 t8;
#pragma unroll
          for (int i = 0; i < 8; ++i) {
            float v = fmaf((float)pa8[kf][i], sa[et],
                      fmaf((float)pb8[kf][i], sb[et],
                           gv[et] * bf2f(w1gb[kf][i])));
            t8[i] = f2bf(fmaxf(v, 0.f));
          }
          bp[et][kf] = t8;
        }
      }
      __builtin_amdgcn_sched_barrier(0);   // keep halves from re-merging
    }

    // ---- layer 2 ----
    f32x4 acc[4][8];
#pragma unroll
    for (int et = 0; et < 4; ++et)
#pragma unroll
      for (int ob = 0; ob < 8; ++ob) acc[et][ob] = z4;
#pragma unroll
    for (int kf = 0; kf < 4; ++kf) {
#pragma unroll
      for (int ob = 0; ob < 8; ++ob) {
        bh8 af = *(const bh8*)&s.w2[((ob * 4 + kf) * 64 + lane) * 8];
#pragma unroll
        for (int et = 0; et < 4; ++et)
          acc[et][ob] = __builtin_amdgcn_mfma_f32_16x16x32_bf16(af, bp[et][kf], acc[et][ob], 0, 0, 0);
      }
    }
#pragma unroll
    for (int et = 0; et < 4; ++et) {
#pragma unroll
      for (int kf = 0; kf < 4; ++kf) {
        bh8 t8;
#pragma unroll
        for (int half = 0; half < 2; ++half) {
          int ob = kf * 2 + half;
#pragma unroll
          for (int r = 0; r < 4; ++r) {
            int f = ob * 16 + q * 4 + r;
            float v = fmaxf(acc[et][ob][r] + s.b2[f], 0.f);
            t8[half * 4 + r] = f2bf(v);
          }
        }
        bp[et][kf] = t8;
      }
    }

    // ---- layer 3 ----
#pragma unroll
    for (int et = 0; et < 4; ++et)
#pragma unroll
      for (int ob = 0; ob < 8; ++ob) acc[et][ob] = z4;
#pragma unroll
    for (int kf = 0; kf < 4; ++kf) {
#pragma unroll
      for (int ob = 0; ob < 8; ++ob) {
        bh8 af = *(const bh8*)&s.w3[((ob * 4 + kf) * 64 + lane) * 8];
#pragma unroll
        for (int et = 0; et < 4; ++et)
          acc[et][ob] = __builtin_amdgcn_mfma_f32_16x16x32_bf16(af, bp[et][kf], acc[et][ob], 0, 0, 0);
      }
    }

    // ---- fused relu3 + layer 4 + sigmoid ----
    float psum[4] = {0.f, 0.f, 0.f, 0.f};
#pragma unroll
    for (int et = 0; et < 4; ++et) {
#pragma unroll
      for (int ob = 0; ob < 8; ++ob) {
#pragma unroll
        for (int r = 0; r < 4; ++r) {
          int f = ob * 16 + q * 4 + r;
          float v = fmaxf(acc[et][ob][r] + s.b3[f], 0.f);
          psum[et] += v * s.w4[f];
        }
      }
    }
#pragma unroll
    for (int et = 0; et < 4; ++et) {
      psum[et] += __shfl_xor(psum[et], 16, 64);
      psum[et] += __shfl_xor(psum[et], 32, 64);
    }
    float vsel = (q == 0) ? psum[0] : (q == 1) ? psum[1] : (q == 2) ? psum[2] : psum[3];
    float val = vsel + b4v;
    float sig = 1.0f / (1.0f + __expf(-val));
    int eout = ebase + lane;
    if (eout < E) __builtin_nontemporal_store(sig, out + eout);
  }
}

extern "C" void kernel_launch(void* const* d_in, const int* in_sizes, int n_in,
                              void* d_out, int out_size, void* d_ws, size_t ws_size,
                              hipStream_t stream) {
  const float* z     = (const float*)d_in[0];
  const float* graph = (const float*)d_in[2];
  const int*   ei    = (const int*)d_in[3];
  const float* W1 = (const float*)d_in[4];
  const float* b1 = (const float*)d_in[5];
  const float* W2 = (const float*)d_in[6];
  const float* b2 = (const float*)d_in[7];
  const float* W3 = (const float*)d_in[8];
  const float* b3 = (const float*)d_in[9];
  const float* W4 = (const float*)d_in[10];
  const float* b4 = (const float*)d_in[11];
  int E  = in_sizes[3] / 2;
  int NN = in_sizes[0] / 128;

  char* w = (char*)d_ws;
  size_t o = 0;
  auto alloc = [&](size_t bytes) { void* p = w + o; o = (o + bytes + 255) & ~(size_t)255; return p; };
  char*   Pai = (char*)alloc((size_t)NN * 128);
  char*   Pbi = (char*)alloc((size_t)NN * 128);
  float*  Pas = (float*)alloc((size_t)NN * 4);
  float*  Pbs = (float*)alloc((size_t)NN * 4);
  ushort* w2f = (ushort*)alloc(16384 * 2);
  ushort* w3f = (ushort*)alloc(16384 * 2);

  hipLaunchKernelGGL(precompute_p, dim3((NN + PNODES - 1) / PNODES), dim3(256), 0, stream,
                     z, W1, b1, Pai, Pbi, Pas, Pbs, NN);
  hipLaunchKernelGGL(pack_w, dim3(32), dim3(512), 0, stream, W2, W3, w2f, w3f);
  hipLaunchKernelGGL(edge_mlp, dim3(NBLOCKS_MAIN), dim3(256), 0, stream,
                     Pai, Pbi, Pas, Pbs, w2f, w3f, graph, ei,
                     W1, b2, b3, W4, b4, (float*)d_out, E, NN);
}